// Round 1
// baseline (247.444 us; speedup 1.0000x reference)
//
#include <hip/hip_runtime.h>
#include <hip/hip_bf16.h>
#include <cmath>

typedef __attribute__((ext_vector_type(8))) short bf16x8;
typedef __attribute__((ext_vector_type(4))) float f32x4;

#define NXC 1024
#define NH 16
#define HD 64
#define BATCH 2
#define SEQ 2048
#define TOK (BATCH * SEQ)

__device__ __forceinline__ ushort f2bf(float f) {
  union { float f; unsigned u; } v; v.f = f;
  unsigned u = v.u;
  unsigned r = (u + 0x7FFFu + ((u >> 16) & 1u)) >> 16;  // RNE
  return (ushort)r;
}

__device__ __forceinline__ void gload_lds16(const void* g, void* lds) {
  __builtin_amdgcn_global_load_lds(
      (const __attribute__((address_space(1))) void*)g,
      (__attribute__((address_space(3))) void*)lds, 16, 0, 0);
}

// ---------------- fp32 -> bf16 convert (X) ----------------
__global__ __launch_bounds__(256) void k_convert(const float* __restrict__ in,
                                                 ushort* __restrict__ out) {
  int i = (blockIdx.x * 256 + threadIdx.x) * 4;
  float4 v = *(const float4*)(in + i);
  ushort4 o;
  o.x = f2bf(v.x); o.y = f2bf(v.y); o.z = f2bf(v.z); o.w = f2bf(v.w);
  *(ushort4*)(out + i) = o;
}

// ---------------- W [K][N] fp32 -> Wt [N][K] bf16 ----------------
__global__ __launch_bounds__(256) void k_transpose_w(const float* __restrict__ in,
                                                     ushort* __restrict__ out,
                                                     int Kd, int Nd) {
  __shared__ float t[32][33];
  int n0 = blockIdx.x * 32, k0 = blockIdx.y * 32;
  int tx = threadIdx.x & 31, ty = threadIdx.x >> 5;
#pragma unroll
  for (int r = 0; r < 4; ++r)
    t[tx][ty + r * 8] = in[(size_t)(k0 + ty + r * 8) * Nd + n0 + tx];
  __syncthreads();
  int nl = threadIdx.x >> 3, kq = (threadIdx.x & 7) * 4;
  ushort4 o;
  o.x = f2bf(t[nl][kq + 0]);
  o.y = f2bf(t[nl][kq + 1]);
  o.z = f2bf(t[nl][kq + 2]);
  o.w = f2bf(t[nl][kq + 3]);
  *(ushort4*)&out[(size_t)(n0 + nl) * Kd + k0 + kq] = o;
}

// ---------------- V [b][h][s][d] -> [b][h][d][s] (bf16) ----------------
__global__ __launch_bounds__(256) void k_transpose_v(const ushort* __restrict__ in,
                                                     ushort* __restrict__ out) {
  __shared__ ushort t[32][33];
  int bh = blockIdx.z;
  int s0 = blockIdx.x * 32, d0 = blockIdx.y * 32;
  const ushort* ip = in + (size_t)bh * SEQ * HD;
  ushort* op = out + (size_t)bh * HD * SEQ;
  int tx = threadIdx.x & 31, ty = threadIdx.x >> 5;
#pragma unroll
  for (int r = 0; r < 4; ++r)
    t[tx][ty + r * 8] = ip[(size_t)(s0 + ty + r * 8) * HD + d0 + tx];
  __syncthreads();
  int dl = threadIdx.x >> 3, sq = (threadIdx.x & 7) * 4;
  ushort4 o;
  o.x = t[dl][sq + 0]; o.y = t[dl][sq + 1];
  o.z = t[dl][sq + 2]; o.w = t[dl][sq + 3];
  *(ushort4*)&op[(size_t)(d0 + dl) * SEQ + s0 + sq] = o;
}

// ---------------- QKV GEMM: C = Xb * Wt^T + b, scatter to q/k/v ----------------
// A: [4096][1024] bf16, Bt: [3072][1024] bf16 (row n holds column n of W)
__global__ __launch_bounds__(256) void k_gemm_qkv(const ushort* __restrict__ A,
                                                  const ushort* __restrict__ Bt,
                                                  const float* __restrict__ bias,
                                                  ushort* __restrict__ q_ws,
                                                  ushort* __restrict__ k_ws,
                                                  ushort* __restrict__ v_tmp) {
  __shared__ ushort As[128 * 64];
  __shared__ ushort Bs[128 * 64];
  const int tid = threadIdx.x;
  const int wave = tid >> 6, lane = tid & 63;
  const int m0 = blockIdx.x * 128, n0 = blockIdx.y * 128;
  const int wr = (wave >> 1) * 64, wc = (wave & 1) * 64;
  const int l15 = lane & 15, lg = lane >> 4;
  f32x4 acc[4][4] = {};
  for (int k0 = 0; k0 < 1024; k0 += 64) {
#pragma unroll
    for (int c = 0; c < 4; ++c) {
      int offB = wave * 4096 + c * 1024 + lane * 16;
      int row = offB >> 7, colB = offB & 127;
      gload_lds16((const char*)A + (size_t)(m0 + row) * 2048 + k0 * 2 + colB,
                  (char*)As + wave * 4096 + c * 1024);
      gload_lds16((const char*)Bt + (size_t)(n0 + row) * 2048 + k0 * 2 + colB,
                  (char*)Bs + wave * 4096 + c * 1024);
    }
    __syncthreads();
#pragma unroll
    for (int kc = 0; kc < 2; ++kc) {
      bf16x8 af[4], bfr[4];
#pragma unroll
      for (int i = 0; i < 4; ++i)
        af[i] = *(const bf16x8*)&As[(wr + i * 16 + l15) * 64 + kc * 32 + lg * 8];
#pragma unroll
      for (int j = 0; j < 4; ++j)
        bfr[j] = *(const bf16x8*)&Bs[(wc + j * 16 + l15) * 64 + kc * 32 + lg * 8];
#pragma unroll
      for (int i = 0; i < 4; ++i)
#pragma unroll
        for (int j = 0; j < 4; ++j)
          acc[i][j] = __builtin_amdgcn_mfma_f32_16x16x32_bf16(af[i], bfr[j], acc[i][j], 0, 0, 0);
    }
    __syncthreads();
  }
  // epilogue: C[row][col], col in [0,3072): sec 0=q (scaled 1/8), 1=k, 2=v
#pragma unroll
  for (int j = 0; j < 4; ++j) {
    int col = n0 + wc + j * 16 + l15;
    float bv = bias[col];
    int sec = col >> 10;
    int within = col & 1023;
    int head = within >> 6, d = within & 63;
#pragma unroll
    for (int i = 0; i < 4; ++i) {
#pragma unroll
      for (int r = 0; r < 4; ++r) {
        int row = m0 + wr + i * 16 + lg * 4 + r;
        int b = row >> 11, s = row & 2047;
        float val = acc[i][j][r] + bv;
        size_t base = ((size_t)(b * NH + head) * SEQ + s) * HD + d;
        if (sec == 0)      q_ws[base] = f2bf(val * 0.125f);
        else if (sec == 1) k_ws[base] = f2bf(val);
        else               v_tmp[base] = f2bf(val);
      }
    }
  }
}

// ---------------- flash attention (causal) ----------------
__global__ __launch_bounds__(256) void k_attn(const ushort* __restrict__ q_ws,
                                              const ushort* __restrict__ k_ws,
                                              const ushort* __restrict__ v_ws,
                                              ushort* __restrict__ a_ws) {
  __shared__ ushort Ks[64 * 64];
  __shared__ ushort Vs[64 * 64];      // [d][key]
  __shared__ ushort Ps[4][16 * 64];   // per-wave P tile
  const int qt = blockIdx.x, bh = blockIdx.y;
  const int tid = threadIdx.x, wave = tid >> 6, lane = tid & 63;
  const int l15 = lane & 15, lg = lane >> 4;
  const ushort* qp = q_ws + (size_t)bh * SEQ * HD;
  const ushort* kp = k_ws + (size_t)bh * SEQ * HD;
  const ushort* vp = v_ws + (size_t)bh * HD * SEQ;
  bf16x8 qf[2];
  {
    int qrow = qt * 64 + wave * 16 + l15;
    qf[0] = *(const bf16x8*)&qp[(size_t)qrow * HD + 0 + lg * 8];
    qf[1] = *(const bf16x8*)&qp[(size_t)qrow * HD + 32 + lg * 8];
  }
  f32x4 o[4] = {};
  float m_r[4] = {-INFINITY, -INFINITY, -INFINITY, -INFINITY};
  float l_r[4] = {0.f, 0.f, 0.f, 0.f};
  for (int kt = 0; kt <= qt; ++kt) {
#pragma unroll
    for (int c = 0; c < 2; ++c) {
      int offB = wave * 2048 + c * 1024 + lane * 16;
      gload_lds16((const char*)kp + (size_t)kt * 8192 + offB,
                  (char*)Ks + wave * 2048 + c * 1024);
      int d = offB >> 7, keyB = offB & 127;
      gload_lds16((const char*)vp + (size_t)d * (SEQ * 2) + (size_t)kt * 128 + keyB,
                  (char*)Vs + wave * 2048 + c * 1024);
    }
    __syncthreads();
    f32x4 sc[4] = {};
    const bool diag = (kt == qt);
#pragma unroll
    for (int kc = 0; kc < 2; ++kc) {
#pragma unroll
      for (int f = 0; f < 4; ++f) {
        if (diag && f > wave) continue;  // fully-masked fragment
        bf16x8 kf = *(const bf16x8*)&Ks[(f * 16 + l15) * 64 + kc * 32 + lg * 8];
        sc[f] = __builtin_amdgcn_mfma_f32_16x16x32_bf16(qf[kc], kf, sc[f], 0, 0, 0);
      }
    }
    if (diag) {
#pragma unroll
      for (int f = 0; f < 4; ++f) {
        int key_rel = f * 16 + l15;
#pragma unroll
        for (int r = 0; r < 4; ++r) {
          int q_rel = wave * 16 + lg * 4 + r;
          if (key_rel > q_rel) sc[f][r] = -1e30f;
        }
      }
    }
    float rmax[4], rsum[4], alpha[4];
#pragma unroll
    for (int r = 0; r < 4; ++r)
      rmax[r] = fmaxf(fmaxf(sc[0][r], sc[1][r]), fmaxf(sc[2][r], sc[3][r]));
#pragma unroll
    for (int off = 1; off < 16; off <<= 1)
#pragma unroll
      for (int r = 0; r < 4; ++r)
        rmax[r] = fmaxf(rmax[r], __shfl_xor(rmax[r], off));
#pragma unroll
    for (int r = 0; r < 4; ++r) {
      float mn = fmaxf(m_r[r], rmax[r]);
      alpha[r] = __expf(m_r[r] - mn);
      m_r[r] = mn;
      rsum[r] = 0.f;
    }
#pragma unroll
    for (int f = 0; f < 4; ++f)
#pragma unroll
      for (int r = 0; r < 4; ++r) {
        float p = __expf(sc[f][r] - m_r[r]);
        sc[f][r] = p;
        rsum[r] += p;
      }
#pragma unroll
    for (int off = 1; off < 16; off <<= 1)
#pragma unroll
      for (int r = 0; r < 4; ++r)
        rsum[r] += __shfl_xor(rsum[r], off);
#pragma unroll
    for (int r = 0; r < 4; ++r)
      l_r[r] = l_r[r] * alpha[r] + rsum[r];
    // P -> bf16 -> per-wave LDS (C-layout -> A-layout re-distribution)
#pragma unroll
    for (int f = 0; f < 4; ++f)
#pragma unroll
      for (int r = 0; r < 4; ++r)
        Ps[wave][(lg * 4 + r) * 64 + f * 16 + l15] = f2bf(sc[f][r]);
#pragma unroll
    for (int df = 0; df < 4; ++df)
#pragma unroll
      for (int r = 0; r < 4; ++r)
        o[df][r] *= alpha[r];
#pragma unroll
    for (int kc = 0; kc < 2; ++kc) {
      bf16x8 pf = *(const bf16x8*)&Ps[wave][l15 * 64 + kc * 32 + lg * 8];
#pragma unroll
      for (int df = 0; df < 4; ++df) {
        bf16x8 vf = *(const bf16x8*)&Vs[(df * 16 + l15) * 64 + kc * 32 + lg * 8];
        o[df] = __builtin_amdgcn_mfma_f32_16x16x32_bf16(pf, vf, o[df], 0, 0, 0);
      }
    }
    __syncthreads();
  }
  int b = bh >> 4, head = bh & 15;
#pragma unroll
  for (int r = 0; r < 4; ++r) {
    float inv = 1.0f / l_r[r];
    int s = qt * 64 + wave * 16 + lg * 4 + r;
#pragma unroll
    for (int df = 0; df < 4; ++df) {
      int col = head * 64 + df * 16 + l15;
      a_ws[((size_t)(b * SEQ + s)) * NXC + col] = f2bf(o[df][r] * inv);
    }
  }
}

// ---------------- out-proj GEMM: out = A * Wt^T + b (fp32 out) ----------------
__global__ __launch_bounds__(256) void k_gemm_proj(const ushort* __restrict__ A,
                                                   const ushort* __restrict__ Bt,
                                                   const float* __restrict__ bias,
                                                   float* __restrict__ out) {
  __shared__ ushort As[128 * 64];
  __shared__ ushort Bs[128 * 64];
  const int tid = threadIdx.x;
  const int wave = tid >> 6, lane = tid & 63;
  const int m0 = blockIdx.x * 128, n0 = blockIdx.y * 128;
  const int wr = (wave >> 1) * 64, wc = (wave & 1) * 64;
  const int l15 = lane & 15, lg = lane >> 4;
  f32x4 acc[4][4] = {};
  for (int k0 = 0; k0 < 1024; k0 += 64) {
#pragma unroll
    for (int c = 0; c < 4; ++c) {
      int offB = wave * 4096 + c * 1024 + lane * 16;
      int row = offB >> 7, colB = offB & 127;
      gload_lds16((const char*)A + (size_t)(m0 + row) * 2048 + k0 * 2 + colB,
                  (char*)As + wave * 4096 + c * 1024);
      gload_lds16((const char*)Bt + (size_t)(n0 + row) * 2048 + k0 * 2 + colB,
                  (char*)Bs + wave * 4096 + c * 1024);
    }
    __syncthreads();
#pragma unroll
    for (int kc = 0; kc < 2; ++kc) {
      bf16x8 af[4], bfr[4];
#pragma unroll
      for (int i = 0; i < 4; ++i)
        af[i] = *(const bf16x8*)&As[(wr + i * 16 + l15) * 64 + kc * 32 + lg * 8];
#pragma unroll
      for (int j = 0; j < 4; ++j)
        bfr[j] = *(const bf16x8*)&Bs[(wc + j * 16 + l15) * 64 + kc * 32 + lg * 8];
#pragma unroll
      for (int i = 0; i < 4; ++i)
#pragma unroll
        for (int j = 0; j < 4; ++j)
          acc[i][j] = __builtin_amdgcn_mfma_f32_16x16x32_bf16(af[i], bfr[j], acc[i][j], 0, 0, 0);
    }
    __syncthreads();
  }
#pragma unroll
  for (int j = 0; j < 4; ++j) {
    int col = n0 + wc + j * 16 + l15;
    float bv = bias[col];
#pragma unroll
    for (int i = 0; i < 4; ++i) {
#pragma unroll
      for (int r = 0; r < 4; ++r) {
        int row = m0 + wr + i * 16 + lg * 4 + r;
        out[(size_t)row * NXC + col] = acc[i][j][r] + bv;
      }
    }
  }
}

extern "C" void kernel_launch(void* const* d_in, const int* in_sizes, int n_in,
                              void* d_out, int out_size, void* d_ws, size_t ws_size,
                              hipStream_t stream) {
  const float* hs       = (const float*)d_in[0];
  const float* c_attn_w = (const float*)d_in[1];
  const float* c_attn_b = (const float*)d_in[2];
  const float* c_proj_w = (const float*)d_in[3];
  const float* c_proj_b = (const float*)d_in[4];
  char* ws = (char*)d_ws;
  const size_t MB = 1 << 20;
  ushort* Xb      = (ushort*)(ws + 0 * MB);   // [4096][1024]
  ushort* Wt_attn = (ushort*)(ws + 8 * MB);   // [3072][1024]
  ushort* Wt_proj = (ushort*)(ws + 14 * MB);  // [1024][1024]
  ushort* q_ws    = (ushort*)(ws + 16 * MB);  // [b][h][s][d]
  ushort* k_ws    = (ushort*)(ws + 24 * MB);  // [b][h][s][d]
  ushort* v_ws    = (ushort*)(ws + 32 * MB);  // [b][h][d][s]
  ushort* a_ws    = (ushort*)(ws + 40 * MB);  // [4096][1024]; also v_tmp before attn
  ushort* v_tmp   = a_ws;

  k_convert<<<4096, 256, 0, stream>>>(hs, Xb);
  k_transpose_w<<<dim3(96, 32), 256, 0, stream>>>(c_attn_w, Wt_attn, 1024, 3072);
  k_transpose_w<<<dim3(32, 32), 256, 0, stream>>>(c_proj_w, Wt_proj, 1024, 1024);
  k_gemm_qkv<<<dim3(32, 24), 256, 0, stream>>>(Xb, Wt_attn, c_attn_b, q_ws, k_ws, v_tmp);
  k_transpose_v<<<dim3(64, 2, 32), 256, 0, stream>>>(v_tmp, v_ws);
  k_attn<<<dim3(32, 32), 256, 0, stream>>>(q_ws, k_ws, v_ws, a_ws);
  k_gemm_proj<<<dim3(32, 8), 256, 0, stream>>>(a_ws, Wt_proj, c_proj_b, (float*)d_out);
}